// Round 18
// baseline (248.201 us; speedup 1.0000x reference)
//
// R18: R17 with NV 24->36 (the last cheap byte-cut). Cached 48/100 rows/group
// (36 VGPR + 12 LDS), stream 52. Est. register demand ~220 < the 256/wave cap
// for 512-thr blocks (R16 spilled at ~272). Byte model (fits R13/R15/R17):
// dur ~= bytes/31GB/s/CU + ~25us serial; 3.6MB -> predict 138-158us.
#include <hip/hip_runtime.h>

#define kT 8
#define kG 120
#define kP 400
#define kObj 45
#define kS 10
#define kHid 200
#define NL 12   // LDS-cached rows per group (rows j0 .. j0+NL-1)
#define NV 36   // VGPR-cached rows per group (rows j0+NL .. j0+NL+NV-1)
#define NC (NL + NV)

__device__ __constant__ int c_gmap[40] = {
    0,1,2,3,4,5,6,7,8,9,
    30,31,32,33,34,35,36,37,38,39,
    60,61,62,63,64,65,66,67,
    84,85,86,87,88,89,
    102,103,104,105,106,107};

__device__ __constant__ float c_freq[5] = {0.01f, 0.7f, 0.91f, 0.97f, 0.99f};

__device__ __forceinline__ float leaky_clamp(float x) {
    x = fminf(fmaxf(x, -1.0f), 1.0f);
    return x > 0.0f ? x : 0.01f * x;
}

__global__ __launch_bounds__(512, 1) void tem_kernel(
    const float* __restrict__ g_seq, const int* __restrict__ x_idx,
    const float* __restrict__ W_comp, const float* __restrict__ W_repeat,
    const float* __restrict__ W_tile, const float* __restrict__ W_tile0,
    const float* __restrict__ w_x, const float* __restrict__ b_x,
    const float* __restrict__ W1, const float* __restrict__ b1,
    const float* __restrict__ W2, const float* __restrict__ b2,
    const float* __restrict__ W_lv1, const float* __restrict__ b_lv1,
    const float* __restrict__ W_lv2, const float* __restrict__ b_lv2,
    float* __restrict__ out)
{
    const int b   = blockIdx.x;
    const int tid = threadIdx.x;
    const int dim = tid;
    const bool hasD = (tid < kP);
    const int wid  = tid >> 6;
    const int lane = tid & 63;
    const int g   = tid >> 7;            // 0..3 matvec group
    const int r   = tid & 127;           // 0..127
    const bool mact = (r < 100);
    const int j0  = g * 100;             // j-quarter

    __shared__ __align__(16) float pT[kP][kT];
    __shared__ __align__(16) float hT[kP][kT];
    __shared__ __align__(16) float lvT[kP][kT];
    __shared__ __align__(16) float xfT[50][kT];
    __shared__ __align__(16) float gdT[40][kT];
    __shared__ __align__(16) float s_wc[4][NL][kP];  // LDS-cached W_lv2 rows
    __shared__ float s_h[kP];
    __shared__ float s_pt[kP];
    __shared__ float s_u[kT][kP];
    __shared__ float s_v[kT][kP];
    __shared__ __align__(16) float s_part[4][kP];
    __shared__ float s_red[2][kT][8];
    __shared__ int   s_idx[kT];
    __shared__ float s_xsp[kS][kS];
    __shared__ float s_xs[kS];
    __shared__ float s_hid[kHid];
    __shared__ float s_lp[8][kObj];

    const float blv1 = hasD ? b_lv1[dim] : 0.0f;
    const float blv2 = hasD ? b_lv2[dim] : 0.0f;
    const float wx   = w_x[0];

    // ================= prologue =================
    if (tid < kT) s_idx[tid] = x_idx[b * kT + tid];
    __syncthreads();

    // LDS cache fill: W_lv2 rows j0..j0+NL-1
    if (mact) {
        #pragma unroll
        for (int k = 0; k < NL; ++k)
            ((float4*)&s_wc[g][k][0])[r] =
                ((const float4*)(W_lv2 + (j0 + k) * kP))[r];
    }

    if (tid < 40) {
        int gi = c_gmap[tid];
        #pragma unroll
        for (int t = 0; t < kT; ++t)
            gdT[tid][t] = g_seq[(b * kT + t) * kG + gi];
    } else if (tid >= 64 && tid < 114) {
        int rr = tid - 64, d = rr % 10;
        float f = c_freq[rr / 10];
        float xf = 0.0f;
        #pragma unroll
        for (int t = 0; t < kT; ++t) {
            float xc = W_comp[s_idx[t] * kS + d];
            xf = (1.0f - f) * xf + f * xc;
            xfT[rr][t] = xf;
        }
    }
    __syncthreads();

    // projections for all 8 t: g_exp, x_exp -> p_inf, h_init
    if (hasD) {
        float ge[kT], xe[kT];
        #pragma unroll
        for (int t = 0; t < kT; ++t) { ge[t] = 0.0f; xe[t] = 0.0f; }
        for (int j = 0; j < 40; ++j) {
            float w = W_repeat[dim * 40 + j];
            float4 gA = *(const float4*)&gdT[j][0];
            float4 gB = *(const float4*)&gdT[j][4];
            ge[0] += w * gA.x; ge[1] += w * gA.y; ge[2] += w * gA.z; ge[3] += w * gA.w;
            ge[4] += w * gB.x; ge[5] += w * gB.y; ge[6] += w * gB.z; ge[7] += w * gB.w;
        }
        for (int j = 0; j < 50; ++j) {
            float w = W_tile[dim * 50 + j];
            float4 xA = *(const float4*)&xfT[j][0];
            float4 xB = *(const float4*)&xfT[j][4];
            xe[0] += w * xA.x; xe[1] += w * xA.y; xe[2] += w * xA.z; xe[3] += w * xA.w;
            xe[4] += w * xB.x; xe[5] += w * xB.y; xe[6] += w * xB.z; xe[7] += w * xB.w;
        }
        float4 pA, pB, hA, hB;
        pA.x = leaky_clamp(ge[0] * xe[0]); pA.y = leaky_clamp(ge[1] * xe[1]);
        pA.z = leaky_clamp(ge[2] * xe[2]); pA.w = leaky_clamp(ge[3] * xe[3]);
        pB.x = leaky_clamp(ge[4] * xe[4]); pB.y = leaky_clamp(ge[5] * xe[5]);
        pB.z = leaky_clamp(ge[6] * xe[6]); pB.w = leaky_clamp(ge[7] * xe[7]);
        hA.x = leaky_clamp(ge[0]); hA.y = leaky_clamp(ge[1]);
        hA.z = leaky_clamp(ge[2]); hA.w = leaky_clamp(ge[3]);
        hB.x = leaky_clamp(ge[4]); hB.y = leaky_clamp(ge[5]);
        hB.z = leaky_clamp(ge[6]); hB.w = leaky_clamp(ge[7]);
        *(float4*)&pT[dim][0] = pA; *(float4*)&pT[dim][4] = pB;
        *(float4*)&hT[dim][0] = hA; *(float4*)&hT[dim][4] = hB;
    }
    __syncthreads();

    // lv1 GEMM for all 8 t: W_lv1 streamed ONCE per block
    if (hasD) {
        float acc[kT];
        #pragma unroll
        for (int t = 0; t < kT; ++t) acc[t] = 0.0f;
        #pragma unroll 4
        for (int j = 0; j < kP; ++j) {
            float w = W_lv1[j * kP + dim];
            float4 pA = *(const float4*)&pT[j][0];
            float4 pB = *(const float4*)&pT[j][4];
            acc[0] += w * pA.x; acc[1] += w * pA.y; acc[2] += w * pA.z; acc[3] += w * pA.w;
            acc[4] += w * pB.x; acc[5] += w * pB.y; acc[6] += w * pB.z; acc[7] += w * pB.w;
        }
        *(float4*)&lvT[dim][0] = make_float4(acc[0], acc[1], acc[2], acc[3]);
        *(float4*)&lvT[dim][4] = make_float4(acc[4], acc[5], acc[6], acc[7]);
    }
    __syncthreads();

    // VGPR cache fill AFTER the high-pressure prologue: rows j0+NL..j0+NC-1
    float4 wreg[NV];
    if (mact) {
        #pragma unroll
        for (int k = 0; k < NV; ++k)
            wreg[k] = ((const float4*)(W_lv2 + (j0 + NL + k) * kP))[r];
    }

    // ================= recurrent steps =================
    int par = 0;
    for (int t = 0; t < kT; ++t) {
        // ---- attractor ----
        float h = hasD ? hT[dim][t] : 0.0f;
        if (t == 0) {
            #pragma unroll
            for (int it = 0; it < 5; ++it) h = leaky_clamp(0.8f * h);
        } else {
            for (int it = 0; it < 5; ++it) {
                for (int s = 0; s < t; ++s) {
                    float p = hasD ? s_v[s][dim] * h : 0.0f;
                    #pragma unroll
                    for (int off = 32; off; off >>= 1) p += __shfl_down(p, off, 64);
                    if (lane == 0) s_red[par][s][wid] = p;
                }
                __syncthreads();
                if (hasD) {
                    float mh = 0.0f;
                    float c = 0.5f;
                    for (int s = t - 1; s >= 0; --s) {
                        float d = 0.0f;
                        #pragma unroll
                        for (int w = 0; w < 8; ++w) d += s_red[par][s][w];
                        mh += c * d * s_u[s][dim];
                        c *= 0.9999f;
                    }
                    h = leaky_clamp(0.8f * h + mh);
                }
                par ^= 1;
            }
        }
        if (hasD) s_h[dim] = h;
        __syncthreads();

        // ---- lv2 matvec: LDS rows + VGPR rows + streamed rows ----
        if (mact) {
            float4 a0{0,0,0,0}, a1{0,0,0,0}, a2{0,0,0,0}, a3{0,0,0,0};
            // LDS-cached rows j0..j0+NL-1
            #pragma unroll
            for (int k = 0; k < NL; k += 4) {
                int j = j0 + k;
                float4 w0 = ((const float4*)&s_wc[g][k+0][0])[r];
                float4 w1v = ((const float4*)&s_wc[g][k+1][0])[r];
                float4 w2v = ((const float4*)&s_wc[g][k+2][0])[r];
                float4 w3 = ((const float4*)&s_wc[g][k+3][0])[r];
                float v0 = s_h[j+0], v1 = s_h[j+1], v2 = s_h[j+2], v3 = s_h[j+3];
                a0.x += w0.x * v0; a0.y += w0.y * v0; a0.z += w0.z * v0; a0.w += w0.w * v0;
                a1.x += w1v.x * v1; a1.y += w1v.y * v1; a1.z += w1v.z * v1; a1.w += w1v.w * v1;
                a2.x += w2v.x * v2; a2.y += w2v.y * v2; a2.z += w2v.z * v2; a2.w += w2v.w * v2;
                a3.x += w3.x * v3; a3.y += w3.y * v3; a3.z += w3.z * v3; a3.w += w3.w * v3;
            }
            // VGPR-cached rows j0+NL..j0+NC-1
            #pragma unroll
            for (int k = 0; k < NV; k += 4) {
                int j = j0 + NL + k;
                float v0 = s_h[j+0], v1 = s_h[j+1], v2 = s_h[j+2], v3 = s_h[j+3];
                a0.x += wreg[k].x * v0; a0.y += wreg[k].y * v0; a0.z += wreg[k].z * v0; a0.w += wreg[k].w * v0;
                a1.x += wreg[k+1].x * v1; a1.y += wreg[k+1].y * v1; a1.z += wreg[k+1].z * v1; a1.w += wreg[k+1].w * v1;
                a2.x += wreg[k+2].x * v2; a2.y += wreg[k+2].y * v2; a2.z += wreg[k+2].z * v2; a2.w += wreg[k+2].w * v2;
                a3.x += wreg[k+3].x * v3; a3.y += wreg[k+3].y * v3; a3.z += wreg[k+3].z * v3; a3.w += wreg[k+3].w * v3;
            }
            // streamed rows j0+NC..j0+99
            #pragma unroll 2
            for (int jj = NC; jj < 100; jj += 4) {
                int j = j0 + jj;
                float4 w0 = ((const float4*)(W_lv2 + (j+0) * kP))[r];
                float4 w1v = ((const float4*)(W_lv2 + (j+1) * kP))[r];
                float4 w2v = ((const float4*)(W_lv2 + (j+2) * kP))[r];
                float4 w3 = ((const float4*)(W_lv2 + (j+3) * kP))[r];
                float v0 = s_h[j+0], v1 = s_h[j+1], v2 = s_h[j+2], v3 = s_h[j+3];
                a0.x += w0.x * v0; a0.y += w0.y * v0; a0.z += w0.z * v0; a0.w += w0.w * v0;
                a1.x += w1v.x * v1; a1.y += w1v.y * v1; a1.z += w1v.z * v1; a1.w += w1v.w * v1;
                a2.x += w2v.x * v2; a2.y += w2v.y * v2; a2.z += w2v.z * v2; a2.w += w2v.w * v2;
                a3.x += w3.x * v3; a3.y += w3.y * v3; a3.z += w3.z * v3; a3.w += w3.w * v3;
            }
            float4 tot;
            tot.x = (a0.x + a1.x) + (a2.x + a3.x);
            tot.y = (a0.y + a1.y) + (a2.y + a3.y);
            tot.z = (a0.z + a1.z) + (a2.z + a3.z);
            tot.w = (a0.w + a1.w) + (a2.w + a3.w);
            ((float4*)&s_part[g][0])[r] = tot;
        }
        __syncthreads();

        // ---- fusion ----
        if (hasD) {
            float lv2raw = (s_part[0][dim] + s_part[1][dim])
                         + (s_part[2][dim] + s_part[3][dim]) + blv2;
            float lv1raw = lvT[dim][t] + blv1;
            float l1 = -2.0f + 6.0f * tanhf(lv1raw * (1.0f / 6.0f));
            float l2 = -2.0f + 6.0f * tanhf(lv2raw * (1.0f / 6.0f));
            float i1v = expf(-l1), i2v = expf(-l2);
            float pinf = pT[dim][t];
            float p = (pinf * i1v + h * i2v) / (i1v + i2v);
            s_pt[dim] = p;
            s_u[t][dim] = p - h;
            s_v[t][dim] = p + h;
        }
        __syncthreads();

        // ---- generative decode ----
        if (tid < 100) {
            int d = tid % 10, c = tid / 10;
            float acc = 0.0f;
            #pragma unroll
            for (int jj = 0; jj < 10; ++jj) {
                int j = c * 10 + jj;
                acc += s_pt[j] * W_tile0[j * kS + d];
            }
            s_xsp[c][d] = acc;
        }
        __syncthreads();
        if (tid < kS) {
            float acc = 0.0f;
            #pragma unroll
            for (int c = 0; c < 10; ++c) acc += s_xsp[c][tid];
            s_xs[tid] = wx * acc + b_x[tid];
        }
        __syncthreads();
        if (tid < kHid) {
            float acc = b1[tid];
            #pragma unroll
            for (int d = 0; d < kS; ++d)
                acc += s_xs[d] * W1[d * kHid + tid];
            s_hid[tid] = acc > 0.0f ? acc : (expf(acc) - 1.0f);
        }
        __syncthreads();
        if (tid < 360) {
            int o = tid % kObj, c = tid / kObj;
            float acc = 0.0f;
            #pragma unroll
            for (int hh = 0; hh < 25; ++hh) {
                int hI = c * 25 + hh;
                acc += s_hid[hI] * W2[hI * kObj + o];
            }
            s_lp[c][o] = acc;
        }
        __syncthreads();
        if (tid < kObj) {
            float acc = b2[tid];
            #pragma unroll
            for (int c = 0; c < 8; ++c) acc += s_lp[c][tid];
            out[(b * kT + t) * kObj + tid] = acc;
        }
        __syncthreads();
    }
}

extern "C" void kernel_launch(void* const* d_in, const int* in_sizes, int n_in,
                              void* d_out, int out_size, void* d_ws, size_t ws_size,
                              hipStream_t stream) {
    const float* g_seq   = (const float*)d_in[0];
    const int*   x_idx   = (const int*)d_in[1];
    const float* W_comp  = (const float*)d_in[2];
    const float* W_repeat= (const float*)d_in[3];
    const float* W_tile  = (const float*)d_in[4];
    const float* W_tile0 = (const float*)d_in[5];
    const float* w_x     = (const float*)d_in[6];
    const float* b_x     = (const float*)d_in[7];
    const float* W1      = (const float*)d_in[8];
    const float* b1      = (const float*)d_in[9];
    const float* W2      = (const float*)d_in[10];
    const float* b2      = (const float*)d_in[11];
    const float* W_lv1   = (const float*)d_in[12];
    const float* b_lv1   = (const float*)d_in[13];
    const float* W_lv2   = (const float*)d_in[14];
    const float* b_lv2   = (const float*)d_in[15];
    float* out = (float*)d_out;

    const int Bn = in_sizes[0] / (kT * kG);
    tem_kernel<<<dim3(Bn), dim3(512), 0, stream>>>(
        g_seq, x_idx, W_comp, W_repeat, W_tile, W_tile0, w_x, b_x,
        W1, b1, W2, b2, W_lv1, b_lv1, W_lv2, b_lv2, out);
}

// Round 19
// 224.352 us; speedup vs baseline: 1.1063x; 1.1063x over previous
//
// R19: revert to R17 exactly (NV=24) — the measured optimum. R18 (NV=36)
// re-spilled (VGPR pinned 128, WRITE 13.7MB, dur +13%); R16 (NV=48) spilled
// hard. Allocator ceiling ~124-128 VGPR for this 8-wave kernel; NV=24 fits.
// Model (fits R13/R15/R17/R18): dur ~= per-block-bytes/31GB/s/CU + 25us.
// R17 streams ~4.15MB -> floor ~159us = measured 158-172. At model floor;
// W_lv2 re-read is sequential-mandatory, LDS 156.7/160KB, VGPR at cap.
#include <hip/hip_runtime.h>

#define kT 8
#define kG 120
#define kP 400
#define kObj 45
#define kS 10
#define kHid 200
#define NL 12   // LDS-cached rows per group (rows j0 .. j0+NL-1)
#define NV 24   // VGPR-cached rows per group (rows j0+NL .. j0+NL+NV-1)
#define NC (NL + NV)

__device__ __constant__ int c_gmap[40] = {
    0,1,2,3,4,5,6,7,8,9,
    30,31,32,33,34,35,36,37,38,39,
    60,61,62,63,64,65,66,67,
    84,85,86,87,88,89,
    102,103,104,105,106,107};

__device__ __constant__ float c_freq[5] = {0.01f, 0.7f, 0.91f, 0.97f, 0.99f};

__device__ __forceinline__ float leaky_clamp(float x) {
    x = fminf(fmaxf(x, -1.0f), 1.0f);
    return x > 0.0f ? x : 0.01f * x;
}

__global__ __launch_bounds__(512, 1) void tem_kernel(
    const float* __restrict__ g_seq, const int* __restrict__ x_idx,
    const float* __restrict__ W_comp, const float* __restrict__ W_repeat,
    const float* __restrict__ W_tile, const float* __restrict__ W_tile0,
    const float* __restrict__ w_x, const float* __restrict__ b_x,
    const float* __restrict__ W1, const float* __restrict__ b1,
    const float* __restrict__ W2, const float* __restrict__ b2,
    const float* __restrict__ W_lv1, const float* __restrict__ b_lv1,
    const float* __restrict__ W_lv2, const float* __restrict__ b_lv2,
    float* __restrict__ out)
{
    const int b   = blockIdx.x;
    const int tid = threadIdx.x;
    const int dim = tid;
    const bool hasD = (tid < kP);
    const int wid  = tid >> 6;
    const int lane = tid & 63;
    const int g   = tid >> 7;            // 0..3 matvec group
    const int r   = tid & 127;           // 0..127
    const bool mact = (r < 100);
    const int j0  = g * 100;             // j-quarter

    __shared__ __align__(16) float pT[kP][kT];
    __shared__ __align__(16) float hT[kP][kT];
    __shared__ __align__(16) float lvT[kP][kT];
    __shared__ __align__(16) float xfT[50][kT];
    __shared__ __align__(16) float gdT[40][kT];
    __shared__ __align__(16) float s_wc[4][NL][kP];  // LDS-cached W_lv2 rows
    __shared__ float s_h[kP];
    __shared__ float s_pt[kP];
    __shared__ float s_u[kT][kP];
    __shared__ float s_v[kT][kP];
    __shared__ __align__(16) float s_part[4][kP];
    __shared__ float s_red[2][kT][8];
    __shared__ int   s_idx[kT];
    __shared__ float s_xsp[kS][kS];
    __shared__ float s_xs[kS];
    __shared__ float s_hid[kHid];
    __shared__ float s_lp[8][kObj];

    const float blv1 = hasD ? b_lv1[dim] : 0.0f;
    const float blv2 = hasD ? b_lv2[dim] : 0.0f;
    const float wx   = w_x[0];

    // ================= prologue =================
    if (tid < kT) s_idx[tid] = x_idx[b * kT + tid];
    __syncthreads();

    // LDS cache fill: W_lv2 rows j0..j0+NL-1
    if (mact) {
        #pragma unroll
        for (int k = 0; k < NL; ++k)
            ((float4*)&s_wc[g][k][0])[r] =
                ((const float4*)(W_lv2 + (j0 + k) * kP))[r];
    }

    if (tid < 40) {
        int gi = c_gmap[tid];
        #pragma unroll
        for (int t = 0; t < kT; ++t)
            gdT[tid][t] = g_seq[(b * kT + t) * kG + gi];
    } else if (tid >= 64 && tid < 114) {
        int rr = tid - 64, d = rr % 10;
        float f = c_freq[rr / 10];
        float xf = 0.0f;
        #pragma unroll
        for (int t = 0; t < kT; ++t) {
            float xc = W_comp[s_idx[t] * kS + d];
            xf = (1.0f - f) * xf + f * xc;
            xfT[rr][t] = xf;
        }
    }
    __syncthreads();

    // projections for all 8 t: g_exp, x_exp -> p_inf, h_init
    if (hasD) {
        float ge[kT], xe[kT];
        #pragma unroll
        for (int t = 0; t < kT; ++t) { ge[t] = 0.0f; xe[t] = 0.0f; }
        for (int j = 0; j < 40; ++j) {
            float w = W_repeat[dim * 40 + j];
            float4 gA = *(const float4*)&gdT[j][0];
            float4 gB = *(const float4*)&gdT[j][4];
            ge[0] += w * gA.x; ge[1] += w * gA.y; ge[2] += w * gA.z; ge[3] += w * gA.w;
            ge[4] += w * gB.x; ge[5] += w * gB.y; ge[6] += w * gB.z; ge[7] += w * gB.w;
        }
        for (int j = 0; j < 50; ++j) {
            float w = W_tile[dim * 50 + j];
            float4 xA = *(const float4*)&xfT[j][0];
            float4 xB = *(const float4*)&xfT[j][4];
            xe[0] += w * xA.x; xe[1] += w * xA.y; xe[2] += w * xA.z; xe[3] += w * xA.w;
            xe[4] += w * xB.x; xe[5] += w * xB.y; xe[6] += w * xB.z; xe[7] += w * xB.w;
        }
        float4 pA, pB, hA, hB;
        pA.x = leaky_clamp(ge[0] * xe[0]); pA.y = leaky_clamp(ge[1] * xe[1]);
        pA.z = leaky_clamp(ge[2] * xe[2]); pA.w = leaky_clamp(ge[3] * xe[3]);
        pB.x = leaky_clamp(ge[4] * xe[4]); pB.y = leaky_clamp(ge[5] * xe[5]);
        pB.z = leaky_clamp(ge[6] * xe[6]); pB.w = leaky_clamp(ge[7] * xe[7]);
        hA.x = leaky_clamp(ge[0]); hA.y = leaky_clamp(ge[1]);
        hA.z = leaky_clamp(ge[2]); hA.w = leaky_clamp(ge[3]);
        hB.x = leaky_clamp(ge[4]); hB.y = leaky_clamp(ge[5]);
        hB.z = leaky_clamp(ge[6]); hB.w = leaky_clamp(ge[7]);
        *(float4*)&pT[dim][0] = pA; *(float4*)&pT[dim][4] = pB;
        *(float4*)&hT[dim][0] = hA; *(float4*)&hT[dim][4] = hB;
    }
    __syncthreads();

    // lv1 GEMM for all 8 t: W_lv1 streamed ONCE per block
    if (hasD) {
        float acc[kT];
        #pragma unroll
        for (int t = 0; t < kT; ++t) acc[t] = 0.0f;
        #pragma unroll 4
        for (int j = 0; j < kP; ++j) {
            float w = W_lv1[j * kP + dim];
            float4 pA = *(const float4*)&pT[j][0];
            float4 pB = *(const float4*)&pT[j][4];
            acc[0] += w * pA.x; acc[1] += w * pA.y; acc[2] += w * pA.z; acc[3] += w * pA.w;
            acc[4] += w * pB.x; acc[5] += w * pB.y; acc[6] += w * pB.z; acc[7] += w * pB.w;
        }
        *(float4*)&lvT[dim][0] = make_float4(acc[0], acc[1], acc[2], acc[3]);
        *(float4*)&lvT[dim][4] = make_float4(acc[4], acc[5], acc[6], acc[7]);
    }
    __syncthreads();

    // VGPR cache fill AFTER the high-pressure prologue: rows j0+NL..j0+NC-1
    float4 wreg[NV];
    if (mact) {
        #pragma unroll
        for (int k = 0; k < NV; ++k)
            wreg[k] = ((const float4*)(W_lv2 + (j0 + NL + k) * kP))[r];
    }

    // ================= recurrent steps =================
    int par = 0;
    for (int t = 0; t < kT; ++t) {
        // ---- attractor ----
        float h = hasD ? hT[dim][t] : 0.0f;
        if (t == 0) {
            #pragma unroll
            for (int it = 0; it < 5; ++it) h = leaky_clamp(0.8f * h);
        } else {
            for (int it = 0; it < 5; ++it) {
                for (int s = 0; s < t; ++s) {
                    float p = hasD ? s_v[s][dim] * h : 0.0f;
                    #pragma unroll
                    for (int off = 32; off; off >>= 1) p += __shfl_down(p, off, 64);
                    if (lane == 0) s_red[par][s][wid] = p;
                }
                __syncthreads();
                if (hasD) {
                    float mh = 0.0f;
                    float c = 0.5f;
                    for (int s = t - 1; s >= 0; --s) {
                        float d = 0.0f;
                        #pragma unroll
                        for (int w = 0; w < 8; ++w) d += s_red[par][s][w];
                        mh += c * d * s_u[s][dim];
                        c *= 0.9999f;
                    }
                    h = leaky_clamp(0.8f * h + mh);
                }
                par ^= 1;
            }
        }
        if (hasD) s_h[dim] = h;
        __syncthreads();

        // ---- lv2 matvec: LDS rows + VGPR rows + streamed rows ----
        if (mact) {
            float4 a0{0,0,0,0}, a1{0,0,0,0}, a2{0,0,0,0}, a3{0,0,0,0};
            // LDS-cached rows j0..j0+NL-1
            #pragma unroll
            for (int k = 0; k < NL; k += 4) {
                int j = j0 + k;
                float4 w0 = ((const float4*)&s_wc[g][k+0][0])[r];
                float4 w1v = ((const float4*)&s_wc[g][k+1][0])[r];
                float4 w2v = ((const float4*)&s_wc[g][k+2][0])[r];
                float4 w3 = ((const float4*)&s_wc[g][k+3][0])[r];
                float v0 = s_h[j+0], v1 = s_h[j+1], v2 = s_h[j+2], v3 = s_h[j+3];
                a0.x += w0.x * v0; a0.y += w0.y * v0; a0.z += w0.z * v0; a0.w += w0.w * v0;
                a1.x += w1v.x * v1; a1.y += w1v.y * v1; a1.z += w1v.z * v1; a1.w += w1v.w * v1;
                a2.x += w2v.x * v2; a2.y += w2v.y * v2; a2.z += w2v.z * v2; a2.w += w2v.w * v2;
                a3.x += w3.x * v3; a3.y += w3.y * v3; a3.z += w3.z * v3; a3.w += w3.w * v3;
            }
            // VGPR-cached rows j0+NL..j0+NC-1
            #pragma unroll
            for (int k = 0; k < NV; k += 4) {
                int j = j0 + NL + k;
                float v0 = s_h[j+0], v1 = s_h[j+1], v2 = s_h[j+2], v3 = s_h[j+3];
                a0.x += wreg[k].x * v0; a0.y += wreg[k].y * v0; a0.z += wreg[k].z * v0; a0.w += wreg[k].w * v0;
                a1.x += wreg[k+1].x * v1; a1.y += wreg[k+1].y * v1; a1.z += wreg[k+1].z * v1; a1.w += wreg[k+1].w * v1;
                a2.x += wreg[k+2].x * v2; a2.y += wreg[k+2].y * v2; a2.z += wreg[k+2].z * v2; a2.w += wreg[k+2].w * v2;
                a3.x += wreg[k+3].x * v3; a3.y += wreg[k+3].y * v3; a3.z += wreg[k+3].z * v3; a3.w += wreg[k+3].w * v3;
            }
            // streamed rows j0+NC..j0+99
            #pragma unroll 2
            for (int jj = NC; jj < 100; jj += 4) {
                int j = j0 + jj;
                float4 w0 = ((const float4*)(W_lv2 + (j+0) * kP))[r];
                float4 w1v = ((const float4*)(W_lv2 + (j+1) * kP))[r];
                float4 w2v = ((const float4*)(W_lv2 + (j+2) * kP))[r];
                float4 w3 = ((const float4*)(W_lv2 + (j+3) * kP))[r];
                float v0 = s_h[j+0], v1 = s_h[j+1], v2 = s_h[j+2], v3 = s_h[j+3];
                a0.x += w0.x * v0; a0.y += w0.y * v0; a0.z += w0.z * v0; a0.w += w0.w * v0;
                a1.x += w1v.x * v1; a1.y += w1v.y * v1; a1.z += w1v.z * v1; a1.w += w1v.w * v1;
                a2.x += w2v.x * v2; a2.y += w2v.y * v2; a2.z += w2v.z * v2; a2.w += w2v.w * v2;
                a3.x += w3.x * v3; a3.y += w3.y * v3; a3.z += w3.z * v3; a3.w += w3.w * v3;
            }
            float4 tot;
            tot.x = (a0.x + a1.x) + (a2.x + a3.x);
            tot.y = (a0.y + a1.y) + (a2.y + a3.y);
            tot.z = (a0.z + a1.z) + (a2.z + a3.z);
            tot.w = (a0.w + a1.w) + (a2.w + a3.w);
            ((float4*)&s_part[g][0])[r] = tot;
        }
        __syncthreads();

        // ---- fusion ----
        if (hasD) {
            float lv2raw = (s_part[0][dim] + s_part[1][dim])
                         + (s_part[2][dim] + s_part[3][dim]) + blv2;
            float lv1raw = lvT[dim][t] + blv1;
            float l1 = -2.0f + 6.0f * tanhf(lv1raw * (1.0f / 6.0f));
            float l2 = -2.0f + 6.0f * tanhf(lv2raw * (1.0f / 6.0f));
            float i1v = expf(-l1), i2v = expf(-l2);
            float pinf = pT[dim][t];
            float p = (pinf * i1v + h * i2v) / (i1v + i2v);
            s_pt[dim] = p;
            s_u[t][dim] = p - h;
            s_v[t][dim] = p + h;
        }
        __syncthreads();

        // ---- generative decode ----
        if (tid < 100) {
            int d = tid % 10, c = tid / 10;
            float acc = 0.0f;
            #pragma unroll
            for (int jj = 0; jj < 10; ++jj) {
                int j = c * 10 + jj;
                acc += s_pt[j] * W_tile0[j * kS + d];
            }
            s_xsp[c][d] = acc;
        }
        __syncthreads();
        if (tid < kS) {
            float acc = 0.0f;
            #pragma unroll
            for (int c = 0; c < 10; ++c) acc += s_xsp[c][tid];
            s_xs[tid] = wx * acc + b_x[tid];
        }
        __syncthreads();
        if (tid < kHid) {
            float acc = b1[tid];
            #pragma unroll
            for (int d = 0; d < kS; ++d)
                acc += s_xs[d] * W1[d * kHid + tid];
            s_hid[tid] = acc > 0.0f ? acc : (expf(acc) - 1.0f);
        }
        __syncthreads();
        if (tid < 360) {
            int o = tid % kObj, c = tid / kObj;
            float acc = 0.0f;
            #pragma unroll
            for (int hh = 0; hh < 25; ++hh) {
                int hI = c * 25 + hh;
                acc += s_hid[hI] * W2[hI * kObj + o];
            }
            s_lp[c][o] = acc;
        }
        __syncthreads();
        if (tid < kObj) {
            float acc = b2[tid];
            #pragma unroll
            for (int c = 0; c < 8; ++c) acc += s_lp[c][tid];
            out[(b * kT + t) * kObj + tid] = acc;
        }
        __syncthreads();
    }
}

extern "C" void kernel_launch(void* const* d_in, const int* in_sizes, int n_in,
                              void* d_out, int out_size, void* d_ws, size_t ws_size,
                              hipStream_t stream) {
    const float* g_seq   = (const float*)d_in[0];
    const int*   x_idx   = (const int*)d_in[1];
    const float* W_comp  = (const float*)d_in[2];
    const float* W_repeat= (const float*)d_in[3];
    const float* W_tile  = (const float*)d_in[4];
    const float* W_tile0 = (const float*)d_in[5];
    const float* w_x     = (const float*)d_in[6];
    const float* b_x     = (const float*)d_in[7];
    const float* W1      = (const float*)d_in[8];
    const float* b1      = (const float*)d_in[9];
    const float* W2      = (const float*)d_in[10];
    const float* b2      = (const float*)d_in[11];
    const float* W_lv1   = (const float*)d_in[12];
    const float* b_lv1   = (const float*)d_in[13];
    const float* W_lv2   = (const float*)d_in[14];
    const float* b_lv2   = (const float*)d_in[15];
    float* out = (float*)d_out;

    const int Bn = in_sizes[0] / (kT * kG);
    tem_kernel<<<dim3(Bn), dim3(512), 0, stream>>>(
        g_seq, x_idx, W_comp, W_repeat, W_tile, W_tile0, w_x, b_x,
        W1, b1, W2, b2, W_lv1, b_lv1, W_lv2, b_lv2, out);
}